// Round 4
// baseline (36673.193 us; speedup 1.0000x reference)
//
#include <hip/hip_runtime.h>
#include <math.h>

// Problem constants
#define B_    512
#define T_    256
#define DIN   64
#define DS    64
#define KK    128   // DIN + DS
#define NN    2048
#define DOUT  10

// Tiling: 512 persistent WGs = NTILES(16) x BTILES(32), 256 thr, 2 WG/CU
#define NT      128
#define BT      16
#define NTILES  (NN / NT)    // 16
#define BTILES  (B_ / BT)    // 32
#define THREADS 256
#define NWG     (NTILES * BTILES)

// Workspace layout (float offsets)
#define PS_ELEMS ((size_t)NTILES * B_ * DS)   // 524288 (2 MB)
#define S_OFF    PS_ELEMS
#define S_ELEMS  ((size_t)B_ * DS)            // 32768
#define ET_OFF   (S_OFF + S_ELEMS)
#define ET_ELEMS ((size_t)KK * NN)            // 262144
#define BAR_OFF  (ET_OFF + ET_ELEMS)
#define BAR_UINTS 2048                        // cnt[32*32] + flag[32*32]

__global__ __launch_bounds__(256) void pre_kernel(const float* __restrict__ enc,
                                                  float* __restrict__ ws,
                                                  float* __restrict__ out) {
    size_t i = (size_t)blockIdx.x * blockDim.x + threadIdx.x;
    size_t stride = (size_t)gridDim.x * blockDim.x;
    for (size_t x = i; x < S_ELEMS; x += stride) ws[S_OFF + x] = 0.0f;     // s0 = 0
    unsigned int* bar = (unsigned int*)(ws + BAR_OFF);
    for (size_t x = i; x < BAR_UINTS; x += stride) bar[x] = 0u;
    for (size_t x = i; x < ET_ELEMS; x += stride) {                        // Et[k][n]
        int k = (int)(x >> 11);
        int n = (int)(x & 2047);
        ws[ET_OFF + x] = enc[(size_t)n * KK + k];
    }
    for (size_t x = i; x < (size_t)B_ * DOUT; x += stride) out[x] = 0.0f;
}

// Plain (non-cooperative) persistent kernel. Co-residency is guaranteed by
// capacity: 512 WGs, __launch_bounds__(256,2) -> 2 WG/CU x 256 CU = 512 slots
// (LDS 25.6 KB/WG, ~80 VGPR). Sync is per-batch-column only (16 WGs), via
// device-scope acquire/release atomics on monotonic generation counters.
__global__ __launch_bounds__(THREADS, 2) void persist_kernel(
    const float* __restrict__ seq,   // [B][T][DIN]
    const float* __restrict__ Et,    // [KK][NN]
    const float* __restrict__ bias,
    const float* __restrict__ gain,
    const float* __restrict__ sd,    // [NN][DS]
    const float* __restrict__ dec,   // [NN][DOUT]
    float* __restrict__ ps,          // [NTILES][B_][DS] partial states
    float* __restrict__ s,           // [B_][DS] reduced state
    unsigned int* __restrict__ bar,  // cnt[32 cols * 32] , flag[32 cols * 32]
    float* __restrict__ out)
{
    __shared__ float xs[BT][132];    // x_aug tile (pad 132)
    __shared__ float As[BT][132];    // activations [row][neuron]
    __shared__ float Ap[NT][17];     // kw=1 partials

    const int tid = threadIdx.x;
    const int nt = blockIdx.x & (NTILES - 1);
    const int bt = blockIdx.x >> 4;
    const int n0 = nt * NT;
    const int b0 = bt * BT;

    unsigned int* cnt  = bar + (size_t)bt * 32;          // one cacheline per column
    unsigned int* flag = bar + 1024 + (size_t)bt * 32;

    // loop-invariant thread mappings
    const int r1 = tid >> 4;           // phase-1/reduce row 0..15
    const int c1 = (tid & 15) << 2;    // phase-1/reduce col group
    const int w   = tid >> 6;
    const int l   = tid & 63;
    const int rw  = w & 1;
    const int kw  = w >> 1;
    const int h   = l >> 5;
    const int q   = l & 31;
    const int k0  = kw * 64 + h * 32;
    const int r0e = rw * 8;
    const int jg  = (l & 15) << 2;     // decode state col group
    const int rgd = w * 4 + (l >> 4);  // decode row 0..15

    for (int t = 0; t < T_; ++t) {
        // ---- phase 1: x_aug = [u_t | s] into LDS ----
        const float4 uv = *(const float4*)&seq[((size_t)(b0 + r1) * T_ + t) * DIN + c1];
        *(float4*)&xs[r1][c1] = uv;
        const float4 sv = *(const float4*)&s[(size_t)(b0 + r1) * DS + c1];
        *(float4*)&xs[r1][DIN + c1] = sv;
        __syncthreads();

        // ---- phase 2: encode (k-split across waves, shfl + LDS reduce) ----
        float4 acc[8];
        #pragma unroll
        for (int r = 0; r < 8; ++r) { acc[r].x = 0.f; acc[r].y = 0.f; acc[r].z = 0.f; acc[r].w = 0.f; }

        #pragma unroll
        for (int b = 0; b < 8; ++b) {
            const int kb = k0 + b * 4;
            const float* ep = &Et[(size_t)kb * NN + n0 + 4 * q];
            const float4 e0 = *(const float4*)(ep);
            const float4 e1 = *(const float4*)(ep + NN);
            const float4 e2 = *(const float4*)(ep + 2 * (size_t)NN);
            const float4 e3 = *(const float4*)(ep + 3 * (size_t)NN);
            #pragma unroll
            for (int r = 0; r < 8; ++r) {
                const float4 xv = *(const float4*)&xs[r0e + r][kb];
                acc[r].x += e0.x * xv.x + e1.x * xv.y + e2.x * xv.z + e3.x * xv.w;
                acc[r].y += e0.y * xv.x + e1.y * xv.y + e2.y * xv.z + e3.y * xv.w;
                acc[r].z += e0.z * xv.x + e1.z * xv.y + e2.z * xv.z + e3.z * xv.w;
                acc[r].w += e0.w * xv.x + e1.w * xv.y + e2.w * xv.z + e3.w * xv.w;
            }
        }

        #pragma unroll
        for (int r = 0; r < 8; ++r) {
            acc[r].x += __shfl_xor(acc[r].x, 32);
            acc[r].y += __shfl_xor(acc[r].y, 32);
            acc[r].z += __shfl_xor(acc[r].z, 32);
            acc[r].w += __shfl_xor(acc[r].w, 32);
        }

        if (w >= 2 && h == 0) {
            #pragma unroll
            for (int r = 0; r < 8; ++r) {
                Ap[4 * q + 0][r0e + r] = acc[r].x;
                Ap[4 * q + 1][r0e + r] = acc[r].y;
                Ap[4 * q + 2][r0e + r] = acc[r].z;
                Ap[4 * q + 3][r0e + r] = acc[r].w;
            }
        }
        __syncthreads();

        if (w < 2 && h == 0) {
            const float4 g4 = *(const float4*)&gain[n0 + 4 * q];
            const float4 b4 = *(const float4*)&bias[n0 + 4 * q];
            #pragma unroll
            for (int r = 0; r < 8; ++r) {
                float4 v = acc[r];
                v.x += Ap[4 * q + 0][r0e + r];
                v.y += Ap[4 * q + 1][r0e + r];
                v.z += Ap[4 * q + 2][r0e + r];
                v.w += Ap[4 * q + 3][r0e + r];
                float4 a;
                a.x = fabsf(g4.x * v.x + b4.x);
                a.y = fabsf(g4.y * v.y + b4.y);
                a.z = fabsf(g4.z * v.z + b4.z);
                a.w = fabsf(g4.w * v.w + b4.w);
                *(float4*)&As[r0e + r][4 * q] = a;
            }
        }
        __syncthreads();

        if (t == T_ - 1) {
            // ---- final projection: out += A_tile @ dec_tile ----
            for (int idx = tid; idx < BT * DOUT; idx += THREADS) {
                const int r = idx / DOUT;
                const int d = idx % DOUT;
                float o = 0.f;
                #pragma unroll 8
                for (int n = 0; n < NT; ++n)
                    o += As[r][n] * dec[(size_t)(n0 + n) * DOUT + d];
                atomicAdd(&out[(size_t)(b0 + r) * DOUT + d], o);
            }
            return;
        }

        // ---- phase 3: decode partial -> ps[nt] ----
        {
            float4 sacc = {0.f, 0.f, 0.f, 0.f};
            #pragma unroll 8
            for (int nb = 0; nb < 32; ++nb) {
                const float4 av = *(const float4*)&As[rgd][nb * 4];
                const float* sp = &sd[(size_t)(n0 + nb * 4) * DS + jg];
                const float4 s0 = *(const float4*)(sp);
                const float4 s1 = *(const float4*)(sp + DS);
                const float4 s2 = *(const float4*)(sp + 2 * DS);
                const float4 s3 = *(const float4*)(sp + 3 * DS);
                sacc.x += av.x * s0.x + av.y * s1.x + av.z * s2.x + av.w * s3.x;
                sacc.y += av.x * s0.y + av.y * s1.y + av.z * s2.y + av.w * s3.y;
                sacc.z += av.x * s0.z + av.y * s1.z + av.z * s2.z + av.w * s3.z;
                sacc.w += av.x * s0.w + av.y * s1.w + av.z * s2.w + av.w * s3.w;
            }
            *(float4*)&ps[((size_t)nt * B_ + b0 + rgd) * DS + jg] = sacc;
        }

        // ---- column sync: 16 WGs arrive; nt==0 reduces; flag releases ----
        __syncthreads();   // all 256 threads' ps stores issued
        if (tid == 0) {
            __threadfence();   // agent release: write back dirty L2 (cross-XCD)
            __hip_atomic_fetch_add(cnt, 1u, __ATOMIC_RELEASE, __HIP_MEMORY_SCOPE_AGENT);
        }

        if (nt == 0) {
            if (tid == 0) {
                while (__hip_atomic_load(cnt, __ATOMIC_ACQUIRE, __HIP_MEMORY_SCOPE_AGENT)
                       < 16u * (unsigned)(t + 1))
                    __builtin_amdgcn_s_sleep(1);
                __threadfence();   // acquire: invalidate stale ps lines
            }
            __syncthreads();
            // reduce 16 partials for this column's rows
            float4 a = {0.f, 0.f, 0.f, 0.f};
            #pragma unroll
            for (int p = 0; p < NTILES; ++p) {
                const float4 v = *(const float4*)&ps[((size_t)p * B_ + b0 + r1) * DS + c1];
                a.x += v.x; a.y += v.y; a.z += v.z; a.w += v.w;
            }
            *(float4*)&s[(size_t)(b0 + r1) * DS + c1] = a;
            __syncthreads();   // all s stores issued
            if (tid == 0) {
                __threadfence();   // agent release for s
                __hip_atomic_store(flag, (unsigned)(t + 1), __ATOMIC_RELEASE, __HIP_MEMORY_SCOPE_AGENT);
            }
        }

        if (tid == 0) {
            while (__hip_atomic_load(flag, __ATOMIC_ACQUIRE, __HIP_MEMORY_SCOPE_AGENT)
                   < (unsigned)(t + 1))
                __builtin_amdgcn_s_sleep(1);
            __threadfence();   // acquire: see fresh s
        }
        __syncthreads();
    }
}

extern "C" void kernel_launch(void* const* d_in, const int* in_sizes, int n_in,
                              void* d_out, int out_size, void* d_ws, size_t ws_size,
                              hipStream_t stream) {
    const float* seq  = (const float*)d_in[0];
    const float* enc  = (const float*)d_in[1];
    const float* bias = (const float*)d_in[2];
    const float* gain = (const float*)d_in[3];
    const float* sd   = (const float*)d_in[4];
    const float* dec  = (const float*)d_in[5];
    float* out = (float*)d_out;
    float* ws  = (float*)d_ws;   // ps | s | Et | barriers  (~3.13 MB)

    pre_kernel<<<dim3(1024), dim3(256), 0, stream>>>(enc, ws, out);

    float* ps = ws;
    float* s  = ws + S_OFF;
    const float* Et = ws + ET_OFF;
    unsigned int* bar = (unsigned int*)(ws + BAR_OFF);

    persist_kernel<<<dim3(NWG), dim3(THREADS), 0, stream>>>(
        seq, Et, bias, gain, sd, dec, ps, s, bar, out);
}

// Round 5
// 7290.964 us; speedup vs baseline: 5.0300x; 5.0300x over previous
//
#include <hip/hip_runtime.h>
#include <math.h>

// Problem constants
#define B_    512
#define T_    256
#define DIN   64
#define DS    64
#define KK    128   // DIN + DS
#define NN    2048
#define DOUT  10

// Tiling: 512 persistent WGs = NTILES(16) x BTILES(32), 256 thr, 2 WG/CU
#define NT      128
#define BT      16
#define NTILES  (NN / NT)    // 16
#define BTILES  (B_ / BT)    // 32
#define THREADS 256
#define NWG     (NTILES * BTILES)

// Workspace layout (float offsets): ps double buffer | Et | counters
#define PS_ELEMS ((size_t)NTILES * B_ * DS)   // 524288 (2 MB) per buffer
#define ET_OFF   (2 * PS_ELEMS)
#define ET_ELEMS ((size_t)KK * NN)            // 262144 (1 MB)
#define BAR_OFF  (ET_OFF + ET_ELEMS)
#define BAR_UINTS 1024                        // cnt[32 cols * 32 pad]

__global__ __launch_bounds__(256) void pre_kernel(const float* __restrict__ enc,
                                                  float* __restrict__ ws,
                                                  float* __restrict__ out) {
    size_t i = (size_t)blockIdx.x * blockDim.x + threadIdx.x;
    size_t stride = (size_t)gridDim.x * blockDim.x;
    unsigned int* bar = (unsigned int*)(ws + BAR_OFF);
    for (size_t x = i; x < BAR_UINTS; x += stride) bar[x] = 0u;
    for (size_t x = i; x < ET_ELEMS; x += stride) {                        // Et[k][n]
        int k = (int)(x >> 11);
        int n = (int)(x & 2047);
        ws[ET_OFF + x] = enc[(size_t)n * KK + k];
    }
    for (size_t x = i; x < (size_t)B_ * DOUT; x += stride) out[x] = 0.0f;
}

// Persistent kernel, FENCE-FREE column sync:
//  - all cross-WG payload moves via relaxed agent-scope atomics (sc1: bypass
//    L1/L2 to the coherence point) -> NO buffer_wbl2 / buffer_inv ever issued,
//    L2 stays warm for Et/sd/seq across all 256 steps.
//  - per batch-column (16 WGs) one monotonic generation counter; producers
//    arrive after s_waitcnt vmcnt(0); consumers poll with RELAXED loads.
//  - ps is double-buffered by step parity; a WG can only reach step t+2
//    (overwriting buf[t&1]) after cnt >= 16*(t+2), which implies every peer
//    finished READING buf[t&1] at step t+1. No reset, no reducer round-trip.
// Co-residency: 512 WGs, __launch_bounds__(256,2) -> 2 WG/CU x 256 CU.
__global__ __launch_bounds__(THREADS, 2) void persist_kernel(
    const float* __restrict__ seq,   // [B][T][DIN]
    const float* __restrict__ Et,    // [KK][NN]
    const float* __restrict__ bias,
    const float* __restrict__ gain,
    const float* __restrict__ sd,    // [NN][DS]
    const float* __restrict__ dec,   // [NN][DOUT]
    float* __restrict__ ps,          // [2][NTILES][B_][DS] partial states
    unsigned int* __restrict__ bar,  // cnt[32 cols * 32]
    float* __restrict__ out)
{
    __shared__ float xs[BT][132];    // x_aug tile (pad 132)
    __shared__ float As[BT][132];    // activations [row][neuron]
    __shared__ float Ap[NT][17];     // kw=1 partials

    const int tid = threadIdx.x;
    const int nt = blockIdx.x & (NTILES - 1);
    const int bt = blockIdx.x >> 4;
    const int n0 = nt * NT;
    const int b0 = bt * BT;

    unsigned int* cnt = bar + (size_t)bt * 32;   // one cacheline per column

    // loop-invariant thread mappings
    const int r1 = tid >> 4;           // phase-1 row 0..15
    const int c1 = (tid & 15) << 2;    // phase-1 col group
    const int w   = tid >> 6;
    const int l   = tid & 63;
    const int rw  = w & 1;
    const int kw  = w >> 1;
    const int h   = l >> 5;
    const int q   = l & 31;
    const int k0  = kw * 64 + h * 32;
    const int r0e = rw * 8;
    const int jg  = (l & 15) << 2;     // decode state col group
    const int rgd = w * 4 + (l >> 4);  // decode row 0..15

    for (int t = 0; t < T_; ++t) {
        // ---- phase 1: x_aug = [u_t | state] into LDS ----
        if (t == 0) {
            float4 z = {0.f, 0.f, 0.f, 0.f};
            *(float4*)&xs[r1][DIN + c1] = z;
        } else {
            if (tid == 0) {
                while (__hip_atomic_load(cnt, __ATOMIC_RELAXED, __HIP_MEMORY_SCOPE_AGENT)
                       < 16u * (unsigned)t)
                    __builtin_amdgcn_s_sleep(1);
            }
            __syncthreads();   // all threads wait for generation t
            const float* pb = ps + (size_t)((t - 1) & 1) * PS_ELEMS;
            float a0 = 0.f, a1 = 0.f, a2 = 0.f, a3 = 0.f;
            #pragma unroll
            for (int p = 0; p < NTILES; ++p) {
                const float* q4 = &pb[((size_t)p * B_ + b0 + r1) * DS + c1];
                a0 += __hip_atomic_load(q4 + 0, __ATOMIC_RELAXED, __HIP_MEMORY_SCOPE_AGENT);
                a1 += __hip_atomic_load(q4 + 1, __ATOMIC_RELAXED, __HIP_MEMORY_SCOPE_AGENT);
                a2 += __hip_atomic_load(q4 + 2, __ATOMIC_RELAXED, __HIP_MEMORY_SCOPE_AGENT);
                a3 += __hip_atomic_load(q4 + 3, __ATOMIC_RELAXED, __HIP_MEMORY_SCOPE_AGENT);
            }
            xs[r1][DIN + c1 + 0] = a0;
            xs[r1][DIN + c1 + 1] = a1;
            xs[r1][DIN + c1 + 2] = a2;
            xs[r1][DIN + c1 + 3] = a3;
        }
        const float4 uv = *(const float4*)&seq[((size_t)(b0 + r1) * T_ + t) * DIN + c1];
        *(float4*)&xs[r1][c1] = uv;
        __syncthreads();

        // ---- phase 2: encode (k-split across waves, shfl + LDS reduce) ----
        float4 acc[8];
        #pragma unroll
        for (int r = 0; r < 8; ++r) { acc[r].x = 0.f; acc[r].y = 0.f; acc[r].z = 0.f; acc[r].w = 0.f; }

        #pragma unroll
        for (int b = 0; b < 8; ++b) {
            const int kb = k0 + b * 4;
            const float* ep = &Et[(size_t)kb * NN + n0 + 4 * q];
            const float4 e0 = *(const float4*)(ep);
            const float4 e1 = *(const float4*)(ep + NN);
            const float4 e2 = *(const float4*)(ep + 2 * (size_t)NN);
            const float4 e3 = *(const float4*)(ep + 3 * (size_t)NN);
            #pragma unroll
            for (int r = 0; r < 8; ++r) {
                const float4 xv = *(const float4*)&xs[r0e + r][kb];
                acc[r].x += e0.x * xv.x + e1.x * xv.y + e2.x * xv.z + e3.x * xv.w;
                acc[r].y += e0.y * xv.x + e1.y * xv.y + e2.y * xv.z + e3.y * xv.w;
                acc[r].z += e0.z * xv.x + e1.z * xv.y + e2.z * xv.z + e3.z * xv.w;
                acc[r].w += e0.w * xv.x + e1.w * xv.y + e2.w * xv.z + e3.w * xv.w;
            }
        }

        #pragma unroll
        for (int r = 0; r < 8; ++r) {
            acc[r].x += __shfl_xor(acc[r].x, 32);
            acc[r].y += __shfl_xor(acc[r].y, 32);
            acc[r].z += __shfl_xor(acc[r].z, 32);
            acc[r].w += __shfl_xor(acc[r].w, 32);
        }

        if (w >= 2 && h == 0) {
            #pragma unroll
            for (int r = 0; r < 8; ++r) {
                Ap[4 * q + 0][r0e + r] = acc[r].x;
                Ap[4 * q + 1][r0e + r] = acc[r].y;
                Ap[4 * q + 2][r0e + r] = acc[r].z;
                Ap[4 * q + 3][r0e + r] = acc[r].w;
            }
        }
        __syncthreads();

        if (w < 2 && h == 0) {
            const float4 g4 = *(const float4*)&gain[n0 + 4 * q];
            const float4 b4 = *(const float4*)&bias[n0 + 4 * q];
            #pragma unroll
            for (int r = 0; r < 8; ++r) {
                float4 v = acc[r];
                v.x += Ap[4 * q + 0][r0e + r];
                v.y += Ap[4 * q + 1][r0e + r];
                v.z += Ap[4 * q + 2][r0e + r];
                v.w += Ap[4 * q + 3][r0e + r];
                float4 a;
                a.x = fabsf(g4.x * v.x + b4.x);
                a.y = fabsf(g4.y * v.y + b4.y);
                a.z = fabsf(g4.z * v.z + b4.z);
                a.w = fabsf(g4.w * v.w + b4.w);
                *(float4*)&As[r0e + r][4 * q] = a;
            }
        }
        __syncthreads();

        if (t == T_ - 1) {
            // ---- final projection: out += A_tile @ dec_tile ----
            for (int idx = tid; idx < BT * DOUT; idx += THREADS) {
                const int r = idx / DOUT;
                const int d = idx % DOUT;
                float o = 0.f;
                #pragma unroll 8
                for (int n = 0; n < NT; ++n)
                    o += As[r][n] * dec[(size_t)(n0 + n) * DOUT + d];
                atomicAdd(&out[(size_t)(b0 + r) * DOUT + d], o);
            }
            return;
        }

        // ---- phase 3: decode partial -> ps[t&1][nt] via sc1 stores ----
        {
            float4 sacc = {0.f, 0.f, 0.f, 0.f};
            #pragma unroll 8
            for (int nb = 0; nb < 32; ++nb) {
                const float4 av = *(const float4*)&As[rgd][nb * 4];
                const float* sp = &sd[(size_t)(n0 + nb * 4) * DS + jg];
                const float4 s0 = *(const float4*)(sp);
                const float4 s1 = *(const float4*)(sp + DS);
                const float4 s2 = *(const float4*)(sp + 2 * DS);
                const float4 s3 = *(const float4*)(sp + 3 * DS);
                sacc.x += av.x * s0.x + av.y * s1.x + av.z * s2.x + av.w * s3.x;
                sacc.y += av.x * s0.y + av.y * s1.y + av.z * s2.y + av.w * s3.y;
                sacc.z += av.x * s0.z + av.y * s1.z + av.z * s2.z + av.w * s3.z;
                sacc.w += av.x * s0.w + av.y * s1.w + av.z * s2.w + av.w * s3.w;
            }
            float* pw = ps + (size_t)(t & 1) * PS_ELEMS
                           + ((size_t)nt * B_ + b0 + rgd) * DS + jg;
            __hip_atomic_store(pw + 0, sacc.x, __ATOMIC_RELAXED, __HIP_MEMORY_SCOPE_AGENT);
            __hip_atomic_store(pw + 1, sacc.y, __ATOMIC_RELAXED, __HIP_MEMORY_SCOPE_AGENT);
            __hip_atomic_store(pw + 2, sacc.z, __ATOMIC_RELAXED, __HIP_MEMORY_SCOPE_AGENT);
            __hip_atomic_store(pw + 3, sacc.w, __ATOMIC_RELAXED, __HIP_MEMORY_SCOPE_AGENT);
        }

        // ---- arrive: drain this thread's sc1 stores, then bump generation ----
        asm volatile("s_waitcnt vmcnt(0)" ::: "memory");
        __syncthreads();   // every thread's stores are at the coherence point
        if (tid == 0)
            __hip_atomic_fetch_add(cnt, 1u, __ATOMIC_RELAXED, __HIP_MEMORY_SCOPE_AGENT);
    }
}

extern "C" void kernel_launch(void* const* d_in, const int* in_sizes, int n_in,
                              void* d_out, int out_size, void* d_ws, size_t ws_size,
                              hipStream_t stream) {
    const float* seq  = (const float*)d_in[0];
    const float* enc  = (const float*)d_in[1];
    const float* bias = (const float*)d_in[2];
    const float* gain = (const float*)d_in[3];
    const float* sd   = (const float*)d_in[4];
    const float* dec  = (const float*)d_in[5];
    float* out = (float*)d_out;
    float* ws  = (float*)d_ws;   // ps[2] | Et | counters  (~5.2 MB)

    pre_kernel<<<dim3(1024), dim3(256), 0, stream>>>(enc, ws, out);

    float* ps = ws;
    const float* Et = ws + ET_OFF;
    unsigned int* bar = (unsigned int*)(ws + BAR_OFF);

    persist_kernel<<<dim3(NWG), dim3(THREADS), 0, stream>>>(
        seq, Et, bias, gain, sd, dec, ps, bar, out);
}

// Round 6
// 6097.349 us; speedup vs baseline: 6.0146x; 1.1958x over previous
//
#include <hip/hip_runtime.h>
#include <math.h>

// Problem constants
#define B_    512
#define T_    256
#define DIN   64
#define DS    64
#define KK    128   // DIN + DS
#define NN    2048
#define DOUT  10

// Tiling: 512 persistent WGs = NTILES(16) x BTILES(32), 256 thr, 2 WG/CU
#define NT      128
#define BT      16
#define NTILES  (NN / NT)    // 16
#define BTILES  (B_ / BT)    // 32
#define THREADS 256
#define NWG     (NTILES * BTILES)

// Workspace layout (float offsets): s rotation buffers | Et | counters
#define S_ELEMS  ((size_t)B_ * DS)            // 32768 (128 KB) per buffer
#define SA_ELEMS (3 * S_ELEMS)                // 3-buffer rotation
#define ET_OFF   SA_ELEMS
#define ET_ELEMS ((size_t)KK * NN)            // 262144 (1 MB)
#define BAR_OFF  (ET_OFF + ET_ELEMS)
#define BAR_UINTS 1024                        // cnt[32 cols * 32 pad]

__global__ __launch_bounds__(256) void pre_kernel(const float* __restrict__ enc,
                                                  float* __restrict__ ws,
                                                  float* __restrict__ out) {
    size_t i = (size_t)blockIdx.x * blockDim.x + threadIdx.x;
    size_t stride = (size_t)gridDim.x * blockDim.x;
    for (size_t x = i; x < SA_ELEMS; x += stride) ws[x] = 0.0f;            // zero all 3 s bufs
    unsigned int* bar = (unsigned int*)(ws + BAR_OFF);
    for (size_t x = i; x < BAR_UINTS; x += stride) bar[x] = 0u;
    for (size_t x = i; x < ET_ELEMS; x += stride) {                        // Et[k][n]
        int k = (int)(x >> 11);
        int n = (int)(x & 2047);
        ws[ET_OFF + x] = enc[(size_t)n * KK + k];
    }
    for (size_t x = i; x < (size_t)B_ * DOUT; x += stride) out[x] = 0.0f;
}

// Persistent kernel, fence-free, ATOMIC-ACCUMULATE state exchange:
//  - state s uses a 3-buffer rotation A[t%3] ([B][DS] each). Producers
//    atomicAdd (relaxed, agent scope -> MALL) their tile's contribution;
//    consumers read the reduced buffer next step (4 KB instead of 64 KB
//    fan-in) -> cross-WG traffic drops ~10x vs R5.
//  - zeroing is rotated in-kernel: at step t (after the phase-1 wait,
//    cnt >= 16t, which proves all peers finished step t-1) each column
//    zeroes A[(t+1)%3]. Peers' step-t+1 adds start only after cnt >= 16(t+1),
//    i.e. after our zero-stores drained (vmcnt(0) before the bump).
//  - no acquire/release fences anywhere: all cross-WG payload moves via
//    relaxed sc1 ops, so L2 stays warm for Et/sd/seq across all 256 steps.
// Co-residency: 512 WGs, __launch_bounds__(256,2) -> 2 WG/CU x 256 CU.
__global__ __launch_bounds__(THREADS, 2) void persist_kernel(
    const float* __restrict__ seq,   // [B][T][DIN]
    const float* __restrict__ Et,    // [KK][NN]
    const float* __restrict__ bias,
    const float* __restrict__ gain,
    const float* __restrict__ sd,    // [NN][DS]
    const float* __restrict__ dec,   // [NN][DOUT]
    float* __restrict__ sA,          // [3][B_][DS] rotating reduced state
    unsigned int* __restrict__ bar,  // cnt[32 cols * 32]
    float* __restrict__ out)
{
    __shared__ float xs[BT][132];    // x_aug tile (pad 132)
    __shared__ float As[BT][132];    // activations [row][neuron]
    __shared__ float Ap[NT][17];     // kw=1 partials

    const int tid = threadIdx.x;
    const int nt = blockIdx.x & (NTILES - 1);
    const int bt = blockIdx.x >> 4;
    const int n0 = nt * NT;
    const int b0 = bt * BT;

    unsigned int* cnt = bar + (size_t)bt * 32;   // one cacheline per column

    // loop-invariant thread mappings
    const int r1 = tid >> 4;           // phase-1 row 0..15
    const int c1 = (tid & 15) << 2;    // phase-1 col group
    const int w   = tid >> 6;
    const int l   = tid & 63;
    const int rw  = w & 1;
    const int kw  = w >> 1;
    const int h   = l >> 5;
    const int q   = l & 31;
    const int k0  = kw * 64 + h * 32;
    const int r0e = rw * 8;
    const int jg  = (l & 15) << 2;     // decode state col group
    const int rgd = w * 4 + (l >> 4);  // decode row 0..15

    for (int t = 0; t < T_; ++t) {
        // ---- phase 1: x_aug = [u_t | s] into LDS; rotate-zero next buffer ----
        const float4 uv = *(const float4*)&seq[((size_t)(b0 + r1) * T_ + t) * DIN + c1];
        *(float4*)&xs[r1][c1] = uv;

        if (t == 0) {
            float4 z = {0.f, 0.f, 0.f, 0.f};
            *(float4*)&xs[r1][DIN + c1] = z;
        } else {
            if (tid == 0) {
                while (__hip_atomic_load(cnt, __ATOMIC_RELAXED, __HIP_MEMORY_SCOPE_AGENT)
                       < 16u * (unsigned)t)
                    __builtin_amdgcn_s_sleep(1);
            }
            __syncthreads();   // all threads see generation t
            const float* pb = sA + (size_t)((t - 1) % 3) * S_ELEMS
                                 + ((size_t)(b0 + r1) * DS + c1);
            xs[r1][DIN + c1 + 0] = __hip_atomic_load(pb + 0, __ATOMIC_RELAXED, __HIP_MEMORY_SCOPE_AGENT);
            xs[r1][DIN + c1 + 1] = __hip_atomic_load(pb + 1, __ATOMIC_RELAXED, __HIP_MEMORY_SCOPE_AGENT);
            xs[r1][DIN + c1 + 2] = __hip_atomic_load(pb + 2, __ATOMIC_RELAXED, __HIP_MEMORY_SCOPE_AGENT);
            xs[r1][DIN + c1 + 3] = __hip_atomic_load(pb + 3, __ATOMIC_RELAXED, __HIP_MEMORY_SCOPE_AGENT);
        }

        // zero A[(t+1)%3] for this column (race-free per the wait above):
        // column region is BT*DS = 1024 floats; WG nt zeroes its 64-float slice.
        if (t < T_ - 2 && tid < 16) {
            float* zb = sA + (size_t)((t + 1) % 3) * S_ELEMS
                           + (size_t)b0 * DS + (size_t)nt * 64 + tid * 4;
            __hip_atomic_store(zb + 0, 0.f, __ATOMIC_RELAXED, __HIP_MEMORY_SCOPE_AGENT);
            __hip_atomic_store(zb + 1, 0.f, __ATOMIC_RELAXED, __HIP_MEMORY_SCOPE_AGENT);
            __hip_atomic_store(zb + 2, 0.f, __ATOMIC_RELAXED, __HIP_MEMORY_SCOPE_AGENT);
            __hip_atomic_store(zb + 3, 0.f, __ATOMIC_RELAXED, __HIP_MEMORY_SCOPE_AGENT);
        }
        __syncthreads();

        // ---- phase 2: encode (k-split across waves, shfl + LDS reduce) ----
        float4 acc[8];
        #pragma unroll
        for (int r = 0; r < 8; ++r) { acc[r].x = 0.f; acc[r].y = 0.f; acc[r].z = 0.f; acc[r].w = 0.f; }

        #pragma unroll
        for (int b = 0; b < 8; ++b) {
            const int kb = k0 + b * 4;
            const float* ep = &Et[(size_t)kb * NN + n0 + 4 * q];
            const float4 e0 = *(const float4*)(ep);
            const float4 e1 = *(const float4*)(ep + NN);
            const float4 e2 = *(const float4*)(ep + 2 * (size_t)NN);
            const float4 e3 = *(const float4*)(ep + 3 * (size_t)NN);
            #pragma unroll
            for (int r = 0; r < 8; ++r) {
                const float4 xv = *(const float4*)&xs[r0e + r][kb];
                acc[r].x += e0.x * xv.x + e1.x * xv.y + e2.x * xv.z + e3.x * xv.w;
                acc[r].y += e0.y * xv.x + e1.y * xv.y + e2.y * xv.z + e3.y * xv.w;
                acc[r].z += e0.z * xv.x + e1.z * xv.y + e2.z * xv.z + e3.z * xv.w;
                acc[r].w += e0.w * xv.x + e1.w * xv.y + e2.w * xv.z + e3.w * xv.w;
            }
        }

        #pragma unroll
        for (int r = 0; r < 8; ++r) {
            acc[r].x += __shfl_xor(acc[r].x, 32);
            acc[r].y += __shfl_xor(acc[r].y, 32);
            acc[r].z += __shfl_xor(acc[r].z, 32);
            acc[r].w += __shfl_xor(acc[r].w, 32);
        }

        if (w >= 2 && h == 0) {
            #pragma unroll
            for (int r = 0; r < 8; ++r) {
                Ap[4 * q + 0][r0e + r] = acc[r].x;
                Ap[4 * q + 1][r0e + r] = acc[r].y;
                Ap[4 * q + 2][r0e + r] = acc[r].z;
                Ap[4 * q + 3][r0e + r] = acc[r].w;
            }
        }
        __syncthreads();

        if (w < 2 && h == 0) {
            const float4 g4 = *(const float4*)&gain[n0 + 4 * q];
            const float4 b4 = *(const float4*)&bias[n0 + 4 * q];
            #pragma unroll
            for (int r = 0; r < 8; ++r) {
                float4 v = acc[r];
                v.x += Ap[4 * q + 0][r0e + r];
                v.y += Ap[4 * q + 1][r0e + r];
                v.z += Ap[4 * q + 2][r0e + r];
                v.w += Ap[4 * q + 3][r0e + r];
                float4 a;
                a.x = fabsf(g4.x * v.x + b4.x);
                a.y = fabsf(g4.y * v.y + b4.y);
                a.z = fabsf(g4.z * v.z + b4.z);
                a.w = fabsf(g4.w * v.w + b4.w);
                *(float4*)&As[r0e + r][4 * q] = a;
            }
        }
        __syncthreads();

        if (t == T_ - 1) {
            // ---- final projection: out += A_tile @ dec_tile ----
            for (int idx = tid; idx < BT * DOUT; idx += THREADS) {
                const int r = idx / DOUT;
                const int d = idx % DOUT;
                float o = 0.f;
                #pragma unroll 8
                for (int n = 0; n < NT; ++n)
                    o += As[r][n] * dec[(size_t)(n0 + n) * DOUT + d];
                atomicAdd(&out[(size_t)(b0 + r) * DOUT + d], o);
            }
            return;
        }

        // ---- phase 3: decode partial, atomic-accumulate into A[t%3] ----
        {
            float4 sacc = {0.f, 0.f, 0.f, 0.f};
            #pragma unroll 8
            for (int nb = 0; nb < 32; ++nb) {
                const float4 av = *(const float4*)&As[rgd][nb * 4];
                const float* sp = &sd[(size_t)(n0 + nb * 4) * DS + jg];
                const float4 s0 = *(const float4*)(sp);
                const float4 s1 = *(const float4*)(sp + DS);
                const float4 s2 = *(const float4*)(sp + 2 * DS);
                const float4 s3 = *(const float4*)(sp + 3 * DS);
                sacc.x += av.x * s0.x + av.y * s1.x + av.z * s2.x + av.w * s3.x;
                sacc.y += av.x * s0.y + av.y * s1.y + av.z * s2.y + av.w * s3.y;
                sacc.z += av.x * s0.z + av.y * s1.z + av.z * s2.z + av.w * s3.z;
                sacc.w += av.x * s0.w + av.y * s1.w + av.z * s2.w + av.w * s3.w;
            }
            float* pw = sA + (size_t)(t % 3) * S_ELEMS
                           + ((size_t)(b0 + rgd) * DS + jg);
            __hip_atomic_fetch_add(pw + 0, sacc.x, __ATOMIC_RELAXED, __HIP_MEMORY_SCOPE_AGENT);
            __hip_atomic_fetch_add(pw + 1, sacc.y, __ATOMIC_RELAXED, __HIP_MEMORY_SCOPE_AGENT);
            __hip_atomic_fetch_add(pw + 2, sacc.z, __ATOMIC_RELAXED, __HIP_MEMORY_SCOPE_AGENT);
            __hip_atomic_fetch_add(pw + 3, sacc.w, __ATOMIC_RELAXED, __HIP_MEMORY_SCOPE_AGENT);
        }

        // ---- arrive: drain adds + zero-stores, then bump generation ----
        asm volatile("s_waitcnt vmcnt(0)" ::: "memory");
        __syncthreads();   // every thread's MALL ops are at the coherence point
        if (tid == 0)
            __hip_atomic_fetch_add(cnt, 1u, __ATOMIC_RELAXED, __HIP_MEMORY_SCOPE_AGENT);
    }
}

extern "C" void kernel_launch(void* const* d_in, const int* in_sizes, int n_in,
                              void* d_out, int out_size, void* d_ws, size_t ws_size,
                              hipStream_t stream) {
    const float* seq  = (const float*)d_in[0];
    const float* enc  = (const float*)d_in[1];
    const float* bias = (const float*)d_in[2];
    const float* gain = (const float*)d_in[3];
    const float* sd   = (const float*)d_in[4];
    const float* dec  = (const float*)d_in[5];
    float* out = (float*)d_out;
    float* ws  = (float*)d_ws;   // sA[3] | Et | counters  (~1.4 MB)

    pre_kernel<<<dim3(1024), dim3(256), 0, stream>>>(enc, ws, out);

    float* sA = ws;
    const float* Et = ws + ET_OFF;
    unsigned int* bar = (unsigned int*)(ws + BAR_OFF);

    persist_kernel<<<dim3(NWG), dim3(THREADS), 0, stream>>>(
        seq, Et, bias, gain, sd, dec, sA, bar, out);
}

// Round 7
// 3510.849 us; speedup vs baseline: 10.4457x; 1.7367x over previous
//
#include <hip/hip_runtime.h>
#include <math.h>

// Problem constants
#define B_    512
#define T_    256
#define DIN   64
#define DS    64
#define KK    128   // DIN + DS
#define NN    2048
#define DOUT  10

// Tiling: 512 WGs = NTILES(4) x BTILES(128), 256 thr, 2 WG/CU.
// NTILES=4 cuts cross-WG exchange 16x vs NTILES=16 (atomic-RMW storm in R6).
#define NT      512
#define BT      4
#define NTILES  (NN / NT)      // 4
#define BTILES  (B_ / BT)      // 128
#define THREADS 256
#define NWG     (NTILES * BTILES)   // 512

// Workspace (float offsets): ps double-buffer | Et | counters
#define PS1      ((size_t)BTILES * NTILES * BT * DS)   // 131072 floats (512 KB)
#define PS_TOT   (2 * PS1)
#define ET_OFF   PS_TOT
#define ET_ELEMS ((size_t)KK * NN)                     // 262144 (1 MB)
#define BAR_OFF  (ET_OFF + ET_ELEMS)
#define BAR_UINTS 4096                                 // 128 cols x 32-uint pad

__global__ __launch_bounds__(256) void pre_kernel(const float* __restrict__ enc,
                                                  float* __restrict__ ws,
                                                  float* __restrict__ out) {
    size_t i = (size_t)blockIdx.x * blockDim.x + threadIdx.x;
    size_t stride = (size_t)gridDim.x * blockDim.x;
    unsigned int* bar = (unsigned int*)(ws + BAR_OFF);
    for (size_t x = i; x < BAR_UINTS; x += stride) bar[x] = 0u;
    for (size_t x = i; x < ET_ELEMS; x += stride) {    // Et[k][n] = enc[n][k]
        int k = (int)(x >> 11);
        int n = (int)(x & 2047);
        ws[ET_OFF + x] = enc[(size_t)n * KK + k];
    }
    for (size_t x = i; x < (size_t)B_ * DOUT; x += stride) out[x] = 0.0f;
}

// Persistent, fence-free, coalesced sc1 exchange:
//  - partial state ps[2][bt][nt][4][64], plain b64 relaxed-agent stores
//    (lane-coalesced, unlike atomics) -> ~2.5 MB/step fabric traffic.
//  - monotonic per-column counter (4 producers); consumer at step t waits
//    cnt >= 4t. Overwrite-safe: a WG writes buf[t&1] only after cnt >= 4t,
//    which implies every peer finished READING buf[(t-2)&1] (same parity)
//    at step t-1 (read precedes write precedes bump).
//  - encode split: u-half (k<64, state-independent) runs BEFORE the poll,
//    hiding peer-arrival latency behind ~1.2 us of compute.
__global__ __launch_bounds__(THREADS, 2) void persist_kernel(
    const float* __restrict__ seq,   // [B][T][DIN]
    const float* __restrict__ Et,    // [KK][NN]
    const float* __restrict__ bias,
    const float* __restrict__ gain,
    const float* __restrict__ sd,    // [NN][DS]
    const float* __restrict__ dec,   // [NN][DOUT]
    float* __restrict__ ps,          // [2][BTILES][NTILES][BT][DS]
    unsigned int* __restrict__ bar,  // cnt[BTILES * 32]
    float* __restrict__ out)
{
    __shared__ float xs[BT][132];    // x_aug tile
    __shared__ float As[BT][516];    // activations [row][neuron 0..511]
    __shared__ float Dp[4][4][65];   // decode cross-wave partials [wave][row][col]

    const int tid = threadIdx.x;
    const int nt = blockIdx.x & (NTILES - 1);
    const int bt = blockIdx.x >> 2;
    const int n0 = nt * NT;
    const int b0 = bt * BT;

    unsigned int* cnt = bar + (size_t)bt * 32;

    const int w = tid >> 6;            // wave 0..3
    const int l = tid & 63;            // lane
    const int nl = w * 128 + 2 * l;    // encode: local neuron pair base
    const int rs = tid >> 6;           // s-exchange row 0..3
    const int cs = tid & 63;           // s-exchange col 0..63

    // loop-invariant per-neuron params (2 neurons/lane)
    const float2 gg = *(const float2*)&gain[n0 + nl];
    const float2 bb = *(const float2*)&bias[n0 + nl];

    for (int t = 0; t < T_; ++t) {
        // ---- stage u_t into xs[.][0..63] ----
        if (tid < 64) {
            const int r = tid >> 4, c = (tid & 15) << 2;
            *(float4*)&xs[r][c] =
                *(const float4*)&seq[((size_t)(b0 + r) * T_ + t) * DIN + c];
        }
        __syncthreads();

        // ---- encode U-half: k = 0..63 (state-independent, hides the poll) ----
        float2 a0 = {0.f,0.f}, a1 = {0.f,0.f}, a2 = {0.f,0.f}, a3 = {0.f,0.f};
        #pragma unroll 4
        for (int k = 0; k < 64; k += 4) {
            const float2 e0 = *(const float2*)&Et[(size_t)(k+0)*NN + n0 + nl];
            const float2 e1 = *(const float2*)&Et[(size_t)(k+1)*NN + n0 + nl];
            const float2 e2 = *(const float2*)&Et[(size_t)(k+2)*NN + n0 + nl];
            const float2 e3 = *(const float2*)&Et[(size_t)(k+3)*NN + n0 + nl];
            const float4 x0 = *(const float4*)&xs[0][k];
            const float4 x1 = *(const float4*)&xs[1][k];
            const float4 x2 = *(const float4*)&xs[2][k];
            const float4 x3 = *(const float4*)&xs[3][k];
            a0.x += e0.x*x0.x + e1.x*x0.y + e2.x*x0.z + e3.x*x0.w;
            a0.y += e0.y*x0.x + e1.y*x0.y + e2.y*x0.z + e3.y*x0.w;
            a1.x += e0.x*x1.x + e1.x*x1.y + e2.x*x1.z + e3.x*x1.w;
            a1.y += e0.y*x1.x + e1.y*x1.y + e2.y*x1.z + e3.y*x1.w;
            a2.x += e0.x*x2.x + e1.x*x2.y + e2.x*x2.z + e3.x*x2.w;
            a2.y += e0.y*x2.x + e1.y*x2.y + e2.y*x2.z + e3.y*x2.w;
            a3.x += e0.x*x3.x + e1.x*x3.y + e2.x*x3.z + e3.x*x3.w;
            a3.y += e0.y*x3.x + e1.y*x3.y + e2.y*x3.z + e3.y*x3.w;
        }

        // ---- acquire state s(t-1): poll + coalesced sc1 fan-in (4 partials) ----
        if (t > 0) {
            if (tid == 0) {
                while (__hip_atomic_load(cnt, __ATOMIC_RELAXED, __HIP_MEMORY_SCOPE_AGENT)
                       < 4u * (unsigned)t)
                    __builtin_amdgcn_s_sleep(1);
            }
            __syncthreads();
            const float* pb = ps + (size_t)((t - 1) & 1) * PS1;
            float ssum = 0.f;
            #pragma unroll
            for (int p = 0; p < NTILES; ++p)
                ssum += __hip_atomic_load(
                    pb + (((size_t)bt * NTILES + p) * BT + rs) * DS + cs,
                    __ATOMIC_RELAXED, __HIP_MEMORY_SCOPE_AGENT);
            xs[rs][DIN + cs] = ssum;
        } else {
            xs[rs][DIN + cs] = 0.f;
        }
        __syncthreads();

        // ---- encode S-half: k = 64..127 ----
        #pragma unroll 4
        for (int k = 64; k < 128; k += 4) {
            const float2 e0 = *(const float2*)&Et[(size_t)(k+0)*NN + n0 + nl];
            const float2 e1 = *(const float2*)&Et[(size_t)(k+1)*NN + n0 + nl];
            const float2 e2 = *(const float2*)&Et[(size_t)(k+2)*NN + n0 + nl];
            const float2 e3 = *(const float2*)&Et[(size_t)(k+3)*NN + n0 + nl];
            const float4 x0 = *(const float4*)&xs[0][k];
            const float4 x1 = *(const float4*)&xs[1][k];
            const float4 x2 = *(const float4*)&xs[2][k];
            const float4 x3 = *(const float4*)&xs[3][k];
            a0.x += e0.x*x0.x + e1.x*x0.y + e2.x*x0.z + e3.x*x0.w;
            a0.y += e0.y*x0.x + e1.y*x0.y + e2.y*x0.z + e3.y*x0.w;
            a1.x += e0.x*x1.x + e1.x*x1.y + e2.x*x1.z + e3.x*x1.w;
            a1.y += e0.y*x1.x + e1.y*x1.y + e2.y*x1.z + e3.y*x1.w;
            a2.x += e0.x*x2.x + e1.x*x2.y + e2.x*x2.z + e3.x*x2.w;
            a2.y += e0.y*x2.x + e1.y*x2.y + e2.y*x2.z + e3.y*x2.w;
            a3.x += e0.x*x3.x + e1.x*x3.y + e2.x*x3.z + e3.x*x3.w;
            a3.y += e0.y*x3.x + e1.y*x3.y + e2.y*x3.z + e3.y*x3.w;
        }

        // ---- activation -> As ----
        {
            float2 v;
            v.x = fabsf(gg.x*a0.x + bb.x); v.y = fabsf(gg.y*a0.y + bb.y);
            *(float2*)&As[0][nl] = v;
            v.x = fabsf(gg.x*a1.x + bb.x); v.y = fabsf(gg.y*a1.y + bb.y);
            *(float2*)&As[1][nl] = v;
            v.x = fabsf(gg.x*a2.x + bb.x); v.y = fabsf(gg.y*a2.y + bb.y);
            *(float2*)&As[2][nl] = v;
            v.x = fabsf(gg.x*a3.x + bb.x); v.y = fabsf(gg.y*a3.y + bb.y);
            *(float2*)&As[3][nl] = v;
        }
        __syncthreads();

        if (t == T_ - 1) {
            // ---- final projection: out += A_tile @ dec_tile ----
            for (int idx = tid; idx < BT * DOUT; idx += THREADS) {
                const int r = idx / DOUT;
                const int d = idx % DOUT;
                float o = 0.f;
                #pragma unroll 8
                for (int n = 0; n < NT; ++n)
                    o += As[r][n] * dec[(size_t)(n0 + n) * DOUT + d];
                atomicAdd(&out[(size_t)(b0 + r) * DOUT + d], o);
            }
            return;
        }

        // ---- decode: wave w sums n-range [w*128, w*128+128), lane = state col ----
        {
            float d0 = 0.f, d1 = 0.f, d2 = 0.f, d3 = 0.f;
            const int nb0 = w * 128;
            #pragma unroll 8
            for (int n = 0; n < 128; ++n) {
                const float sv = sd[(size_t)(n0 + nb0 + n) * DS + l];  // coalesced b32
                const float av0 = As[0][nb0 + n];   // LDS broadcast
                const float av1 = As[1][nb0 + n];
                const float av2 = As[2][nb0 + n];
                const float av3 = As[3][nb0 + n];
                d0 += av0 * sv; d1 += av1 * sv; d2 += av2 * sv; d3 += av3 * sv;
            }
            if (w > 0) {
                Dp[w][0][l] = d0; Dp[w][1][l] = d1;
                Dp[w][2][l] = d2; Dp[w][3][l] = d3;
            }
            __syncthreads();
            if (w == 0) {
                #pragma unroll
                for (int p = 1; p < 4; ++p) {
                    d0 += Dp[p][0][l]; d1 += Dp[p][1][l];
                    d2 += Dp[p][2][l]; d3 += Dp[p][3][l];
                }
                // write this WG's partial: ps[t&1][bt][nt][r][l], coalesced sc1
                float* pw = ps + (size_t)(t & 1) * PS1
                               + (((size_t)bt * NTILES + nt) * BT) * DS + l;
                __hip_atomic_store(pw + 0*DS, d0, __ATOMIC_RELAXED, __HIP_MEMORY_SCOPE_AGENT);
                __hip_atomic_store(pw + 1*DS, d1, __ATOMIC_RELAXED, __HIP_MEMORY_SCOPE_AGENT);
                __hip_atomic_store(pw + 2*DS, d2, __ATOMIC_RELAXED, __HIP_MEMORY_SCOPE_AGENT);
                __hip_atomic_store(pw + 3*DS, d3, __ATOMIC_RELAXED, __HIP_MEMORY_SCOPE_AGENT);
            }
        }

        // ---- arrive: drain sc1 stores, bump generation ----
        asm volatile("s_waitcnt vmcnt(0)" ::: "memory");
        __syncthreads();
        if (tid == 0)
            __hip_atomic_fetch_add(cnt, 1u, __ATOMIC_RELAXED, __HIP_MEMORY_SCOPE_AGENT);
    }
}

extern "C" void kernel_launch(void* const* d_in, const int* in_sizes, int n_in,
                              void* d_out, int out_size, void* d_ws, size_t ws_size,
                              hipStream_t stream) {
    const float* seq  = (const float*)d_in[0];
    const float* enc  = (const float*)d_in[1];
    const float* bias = (const float*)d_in[2];
    const float* gain = (const float*)d_in[3];
    const float* sd   = (const float*)d_in[4];
    const float* dec  = (const float*)d_in[5];
    float* out = (float*)d_out;
    float* ws  = (float*)d_ws;   // ps[2] | Et | counters  (~2.1 MB)

    pre_kernel<<<dim3(1024), dim3(256), 0, stream>>>(enc, ws, out);

    float* ps = ws;
    const float* Et = ws + ET_OFF;
    unsigned int* bar = (unsigned int*)(ws + BAR_OFF);

    persist_kernel<<<dim3(NWG), dim3(THREADS), 0, stream>>>(
        seq, Et, bias, gain, sd, dec, ps, bar, out);
}